// Round 12
// baseline (6548.778 us; speedup 1.0000x reference)
//
#include <hip/hip_runtime.h>
#include <stdint.h>

#define BB 256
#define TT 512
#define HH 512
#define NBLK 256
#define SSTR 16
#define BBHH (BB*HH)

typedef __bf16 bf16x8 __attribute__((ext_vector_type(8)));
typedef float f32x4 __attribute__((ext_vector_type(4)));
typedef unsigned int u32x2 __attribute__((ext_vector_type(2)));

static __device__ __forceinline__ unsigned short f2bf(float f) {
    unsigned int u = __builtin_bit_cast(unsigned int, f);
    return (unsigned short)((u + 0x7fffu + ((u >> 16) & 1u)) >> 16);
}
static __device__ __forceinline__ bf16x8 packbf8(const float* p) {
    float4 a = *reinterpret_cast<const float4*>(p);
    float4 b = *reinterpret_cast<const float4*>(p + 4);
    unsigned short us[8] = { f2bf(a.x), f2bf(a.y), f2bf(a.z), f2bf(a.w),
                             f2bf(b.x), f2bf(b.y), f2bf(b.z), f2bf(b.w) };
    uint4 u; __builtin_memcpy(&u, us, 16);
    return __builtin_bit_cast(bf16x8, u);
}
static __device__ __forceinline__ float sigm(float x){ return 1.0f/(1.0f+__expf(-x)); }
static __device__ __forceinline__ float tanh_fast(float x){ return 2.0f/(1.0f+__expf(-2.0f*x)) - 1.0f; }

// system-coherent (LLC) path — PROVEN primitives
static __device__ __forceinline__ void ld_sys(uint4& d, const void* p) {
    asm volatile("global_load_dwordx4 %0, %1, off sc0 sc1" : "=v"(d) : "v"(p));
}
static __device__ __forceinline__ void st_sys2(void* p, u32x2 v) {
    asm volatile("global_store_dwordx2 %0, %1, off sc0 sc1" :: "v"(p), "v"(v) : "memory");
}
#define WAITVM(N) asm volatile("s_waitcnt vmcnt(" #N ")" ::: "memory")
#define SBAR      __builtin_amdgcn_sched_barrier(0)

__global__ __launch_bounds__(256) void prep_zero(unsigned short* __restrict__ h1p3,
                                                 unsigned short* __restrict__ h2p1,
                                                 int* __restrict__ slots) {
    int i = blockIdx.x * blockDim.x + threadIdx.x;
    for (int k = i; k < BBHH; k += gridDim.x * blockDim.x) { h1p3[k] = 0; h2p1[k] = 0; }
    if (i < NBLK * SSTR) slots[i] = 0;
}

// Persistent pipelined 2-layer LSTM — R11 exchange/sync, 8 waves/block (2/SIMD)
// for latency hiding. 256 blocks x 512 thr = 1 block/CU, 8 waves/CU.
// Groups of 32 rows: 16 L0 blocks (bid=g*16+cs) + 16 L1 blocks (bid=128+g*16+cs),
// block tile 32 rows x 32 cols.
// L0 wave w(0..7): K-eighth (64) of Whh0; wb[2][2][4]=64 regs, 4 A-loads, 32 MFMA.
// L1 wave w: mm=w>>2, kh=w&3 -> K-quarter (128) of (mm? Whh1:Wih1); wb[2][4][4]=128
// regs, 8 A-loads, 64 MFMA  (== proven R7-L0 register profile, no spill).
// Reduce (64KB LDS, 4 slots x 16KB, XOR-swizzled): phase A: waves 4-7 dump ->
// slot w-4; phase B: waves 0-3 add slot w (pair w/w+4 combines K/mm pieces) and
// redump slot w; epilogue: waves 0-3 gather 4 slots, lane-owned c, 8B/lane store.
// SYNC: decoupled slot barrier (R11): L0@ns waits L0>=ns, L1>=ns-3 (h1 4-deep);
// L1@ns waits L0>=ns, L1>=ns-1. Release = vmcnt(0)+syncthreads+agent slot store.
__global__ __launch_bounds__(512, 1) void lstm_persist(
    const float* __restrict__ x,        // [B][T]
    const float* __restrict__ wih0,     // [2048]
    const float* __restrict__ Whh0,     // [2048][512] f32
    const float* __restrict__ Wih1,     // [2048][512] f32
    const float* __restrict__ Whh1,     // [2048][512] f32
    unsigned short* __restrict__ h1buf, // 4 x [B][H] bf16 (parity t&3)
    unsigned short* __restrict__ h2buf, // 2 x [B][H] bf16 (parity t&1)
    int* __restrict__ slots)
{
    __shared__ float xf[16384];         // 64 KB: [4 slot][2 rt][2 nt][16 row][16 col][4 g]

    const int tid = threadIdx.x;
    const int w   = tid >> 6;           // 0..7
    const int l   = tid & 63;
    const int ln  = l & 15;
    const int kq  = l >> 4;
    const int bid = blockIdx.x;
    const bool isL0 = bid < 128;

    int g, cs, k0, mm = 0;
    const float* Wsrc;
    if (isL0) {
        g = bid >> 4; cs = bid & 15;
        k0 = w * 64;
        Wsrc = Whh0;
    } else {
        const int q = bid - 128;
        g = q >> 4; cs = q & 15;
        mm = w >> 2;
        k0 = (w & 3) * 128;
        Wsrc = mm ? Whh1 : Wih1;
    }
    const int NKB = isL0 ? 2 : 4;       // kb count (K = NKB*32 per wave)

    // ---- one-time weight preload (L0: 64 regs, L1: 128 regs) ----
    bf16x8 wb[2][4][4];
    #pragma unroll
    for (int nt = 0; nt < 2; ++nt)
        for (int kb = 0; kb < NKB; ++kb)
            #pragma unroll
            for (int g4 = 0; g4 < 4; ++g4)
                wb[nt][kb][g4] = packbf8(Wsrc + (size_t)(g4 * HH + cs * 32 + nt * 16 + ln) * HH + k0 + kb * 32 + kq * 8);

    // epilogue constants (waves 0-3 own 8 rows each)
    const int erow = g * 32 + (w & 3) * 8 + (l >> 3);
    f32x4 wiv[4] = {};
    if (isL0 && w < 4) {
        #pragma unroll
        for (int j = 0; j < 4; ++j) {
            const int cg = cs * 32 + (l & 7) * 4 + j;
            wiv[j] = (f32x4){ wih0[cg], wih0[512 + cg], wih0[1024 + cg], wih0[1536 + cg] };
        }
    }
    const int rt_r = (w & 3) >> 1;
    const int rowl = (w & 1) * 8 + (l >> 3);
    const int nt_r = (l >> 2) & 1;
    const int colb = (l & 3) * 4;

    float cst[4] = {0.f, 0.f, 0.f, 0.f};

    for (int s = 0; s <= TT; ++s) {
        const bool active = isL0 ? (s < TT) : (s >= 1);
        if (active) {
            const int t = isL0 ? s : s - 1;
            const unsigned short* hp;
            if (isL0)    hp = h1buf + (size_t)((t - 1) & 3) * BBHH;  // h1_{t-1}
            else if (mm) hp = h2buf + (size_t)((t - 1) & 1) * BBHH;  // h2_{t-1}
            else         hp = h1buf + (size_t)(t & 3) * BBHH;        // h1_t

            f32x4 acc[2][2][4];
            #pragma unroll
            for (int rt = 0; rt < 2; ++rt)
                #pragma unroll
                for (int nt = 0; nt < 2; ++nt)
                    #pragma unroll
                    for (int g4 = 0; g4 < 4; ++g4) acc[rt][nt][g4] = (f32x4){0.f,0.f,0.f,0.f};

            const char* ab = (const char*)(hp + (size_t)(g * 32 + ln) * HH + k0 + kq * 8);
            uint4 A[4][2];

            #define MK(kb, ap) do { \
                _Pragma("unroll") \
                for (int rt = 0; rt < 2; ++rt) { \
                    bf16x8 av = __builtin_bit_cast(bf16x8, A[ap][rt]); \
                    _Pragma("unroll") \
                    for (int nt = 0; nt < 2; ++nt) \
                        _Pragma("unroll") \
                        for (int g4 = 0; g4 < 4; ++g4) \
                            acc[rt][nt][g4] = __builtin_amdgcn_mfma_f32_16x16x32_bf16(av, wb[nt][kb][g4], acc[rt][nt][g4], 0, 0, 0); \
                } } while (0)

            if (isL0) {
                #pragma unroll
                for (int kb = 0; kb < 2; ++kb) {
                    ld_sys(A[kb][0], ab + kb * 64);
                    ld_sys(A[kb][1], ab + 16384 + kb * 64);
                }
                WAITVM(2); SBAR; MK(0, 0);
                WAITVM(0); SBAR; MK(1, 1);
            } else {
                #pragma unroll
                for (int kb = 0; kb < 4; ++kb) {
                    ld_sys(A[kb][0], ab + kb * 64);
                    ld_sys(A[kb][1], ab + 16384 + kb * 64);
                }
                WAITVM(6); SBAR; MK(0, 0);
                WAITVM(4); SBAR; MK(1, 1);
                WAITVM(2); SBAR; MK(2, 2);
                WAITVM(0); SBAR; MK(3, 3);
            }
            #undef MK

            // ---- phase A: waves 4-7 dump acc -> slot (w-4) ----
            if (w >= 4) {
                const int s4 = w - 4;
                #pragma unroll
                for (int rt = 0; rt < 2; ++rt)
                    #pragma unroll
                    for (int nt = 0; nt < 2; ++nt)
                        #pragma unroll
                        for (int r = 0; r < 4; ++r) {
                            const int row16 = kq * 4 + r;
                            f32x4 v = { acc[rt][nt][0][r], acc[rt][nt][1][r],
                                        acc[rt][nt][2][r], acc[rt][nt][3][r] };
                            *(f32x4*)((char*)xf + (((s4 * 2 + rt) * 2 + nt) * 16 + row16) * 256
                                                + ((ln * 16) ^ ((row16 & 7) << 4))) = v;
                        }
            }
            __syncthreads();
            // ---- phase B: waves 0-3 add pair slot, redump ----
            if (w < 4) {
                #pragma unroll
                for (int rt = 0; rt < 2; ++rt)
                    #pragma unroll
                    for (int nt = 0; nt < 2; ++nt)
                        #pragma unroll
                        for (int r = 0; r < 4; ++r) {
                            const int row16 = kq * 4 + r;
                            char* p = (char*)xf + (((w * 2 + rt) * 2 + nt) * 16 + row16) * 256
                                               + ((ln * 16) ^ ((row16 & 7) << 4));
                            f32x4 v = *(const f32x4*)p;
                            v.x += acc[rt][nt][0][r]; v.y += acc[rt][nt][1][r];
                            v.z += acc[rt][nt][2][r]; v.w += acc[rt][nt][3][r];
                            *(f32x4*)p = v;
                        }
            }
            __syncthreads();

            // ---- epilogue (waves 0-3): gather 4 slots, cell update, store ----
            if (w < 4) {
                float xv = 0.f;
                if (isL0) xv = x[(size_t)erow * TT + t];
                unsigned short* ho = isL0 ? (h1buf + (size_t)(t & 3) * BBHH)
                                          : (h2buf + (size_t)(t & 1) * BBHH);
                unsigned short hout[4];
                #pragma unroll
                for (int j = 0; j < 4; ++j) {
                    f32x4 sv = (f32x4){0.f, 0.f, 0.f, 0.f};
                    #pragma unroll
                    for (int s4 = 0; s4 < 4; ++s4)
                        sv += *(const f32x4*)((const char*)xf + (((s4 * 2 + rt_r) * 2 + nt_r) * 16 + rowl) * 256
                                                              + (((colb + j) * 16) ^ ((rowl & 7) << 4)));
                    if (isL0) sv += wiv[j] * xv;
                    const float c = sigm(sv.y) * cst[j] + sigm(sv.x) * tanh_fast(sv.z);
                    cst[j] = c;
                    hout[j] = f2bf(sigm(sv.w) * tanh_fast(c));
                }
                u32x2 hv;
                hv.x = (unsigned int)hout[0] | ((unsigned int)hout[1] << 16);
                hv.y = (unsigned int)hout[2] | ((unsigned int)hout[3] << 16);
                st_sys2(ho + (size_t)erow * HH + cs * 32 + (l & 7) * 4, hv);
            }
        }

        // ---- decoupled release + layer-local acquire (R11-proven) ----
        if (s < TT) {
            WAITVM(0);
            __syncthreads();
            if (active && tid == 0)
                __hip_atomic_store(slots + bid * SSTR, isL0 ? s + 1 : s,
                                   __ATOMIC_RELAXED, __HIP_MEMORY_SCOPE_AGENT);
            const int ns = s + 1;
            const bool nextAct = isL0 ? (ns < TT) : true;
            if (nextAct) {
                if (tid < 32) {
                    const int* sp;
                    int thr;
                    if (tid < 16) {
                        sp  = slots + (g * 16 + tid) * SSTR;
                        thr = ns;
                    } else {
                        sp  = slots + (128 + g * 16 + (tid - 16)) * SSTR;
                        thr = isL0 ? ns - 3 : ns - 1;
                    }
                    while (__hip_atomic_load(sp, __ATOMIC_RELAXED, __HIP_MEMORY_SCOPE_AGENT) < thr)
                        __builtin_amdgcn_s_sleep(2);
                }
                SBAR;
                __syncthreads();
            }
        }
    }
}

// ---- final: LayerNorm(last h2) @ w_out^T, one 64-lane block per batch row ----
__global__ __launch_bounds__(64) void ln_out_k(const unsigned short* __restrict__ h2,
                                               const float* __restrict__ gamma,
                                               const float* __restrict__ beta,
                                               const float* __restrict__ wout,
                                               float* __restrict__ out)
{
    const int row = blockIdx.x;
    const int lane = threadIdx.x;
    uint4 u = *reinterpret_cast<const uint4*>(h2 + row * HH + lane * 8);
    unsigned short us[8];
    *reinterpret_cast<uint4*>(us) = u;
    float v[8];
    #pragma unroll
    for (int j = 0; j < 8; ++j) {
        unsigned int ww = ((unsigned int)us[j]) << 16;
        v[j] = __builtin_bit_cast(float, ww);
    }
    float sum = 0.f;
    #pragma unroll
    for (int j = 0; j < 8; ++j) sum += v[j];
    #pragma unroll
    for (int o = 32; o >= 1; o >>= 1) sum += __shfl_xor(sum, o);
    const float mu = sum * (1.0f / 512.0f);

    float vs = 0.f;
    #pragma unroll
    for (int j = 0; j < 8; ++j) { float d = v[j] - mu; vs += d * d; }
    #pragma unroll
    for (int o = 32; o >= 1; o >>= 1) vs += __shfl_xor(vs, o);
    const float inv = rsqrtf(vs * (1.0f / 512.0f) + 1e-5f);

    float dot = 0.f;
    #pragma unroll
    for (int j = 0; j < 8; ++j) {
        const int c = lane * 8 + j;
        dot += ((v[j] - mu) * inv * gamma[c] + beta[c]) * wout[c];
    }
    #pragma unroll
    for (int o = 32; o >= 1; o >>= 1) dot += __shfl_xor(dot, o);
    if (lane == 0) out[row] = dot;
}

extern "C" void kernel_launch(void* const* d_in, const int* in_sizes, int n_in,
                              void* d_out, int out_size, void* d_ws, size_t ws_size,
                              hipStream_t stream) {
    const float* x     = (const float*)d_in[0];
    const float* wih0  = (const float*)d_in[1];
    const float* whh0  = (const float*)d_in[2];
    const float* wih1  = (const float*)d_in[3];
    const float* whh1  = (const float*)d_in[4];
    const float* gamma = (const float*)d_in[5];
    const float* beta  = (const float*)d_in[6];
    const float* wout  = (const float*)d_in[7];

    // ws layout: h1buf 4x256KB | h2buf 2x256KB | slots 16KB
    char* ws = (char*)d_ws;
    unsigned short* h1buf = (unsigned short*)(ws);
    unsigned short* h2buf = (unsigned short*)(ws + (1024u << 10));
    int* slots            = (int*)(ws + (1536u << 10));

    hipLaunchKernelGGL(prep_zero, dim3(64), dim3(256), 0, stream,
                       h1buf + 3 * (size_t)BBHH, h2buf + BBHH, slots);

    hipLaunchKernelGGL(lstm_persist, dim3(NBLK), dim3(512), 0, stream,
                       x, wih0, whh0, wih1, whh1, h1buf, h2buf, slots);

    // final h2 is parity (T-1)&1 == 1
    hipLaunchKernelGGL(ln_out_k, dim3(BB), dim3(64), 0, stream,
                       h2buf + BBHH, gamma, beta, wout, (float*)d_out);
}